// Round 12
// baseline (1162.714 us; speedup 1.0000x reference)
//
#include <hip/hip_runtime.h>
#include <hip/hip_bf16.h>
#include <cstddef>

#define BSZ 16
#define NPT 1024
#define KNN 30
#define TKR 9
#define FLT_BIG 3.402823466e+38f
#define DBL_BIG 1.0e300

__device__ __forceinline__ float gelu_f(float x) {
    return 0.5f * x * (1.0f + erff(x * 0.7071067811865476f));
}

// ---------------------------------------------------------------------------
// 1. prep_all: layer 0 = transpose x; layers 1..4 = WZ_l = [W;S;pad]
// ---------------------------------------------------------------------------
__global__ __launch_bounds__(256) void prep_all(
    const float* __restrict__ x, float* __restrict__ pts,
    const float* __restrict__ W1, const float* __restrict__ S1, float* __restrict__ wz1,
    const float* __restrict__ W2, const float* __restrict__ S2, float* __restrict__ wz2,
    const float* __restrict__ W3, const float* __restrict__ S3, float* __restrict__ wz3,
    const float* __restrict__ W4, const float* __restrict__ S4, float* __restrict__ wz4) {
    int layer = blockIdx.y;
    int t = blockIdx.x * 256 + threadIdx.x;
    if (layer == 0) {
        if (t >= BSZ * NPT) return;
        int b = t >> 10, n = t & 1023;
        const float* xp = x + (size_t)b * 3 * NPT;
        pts[t * 3 + 0] = xp[n];
        pts[t * 3 + 1] = xp[NPT + n];
        pts[t * 3 + 2] = xp[2 * NPT + n];
        return;
    }
    const float *W, *S; float* WZ; int KW, KS, N, kpad;
    if (layer == 1)      { W = W1; S = S1; WZ = wz1; KW = 27;   KS = 3;   N = 64;  kpad = 32;   }
    else if (layer == 2) { W = W2; S = S2; WZ = wz2; KW = 576;  KS = 64;  N = 64;  kpad = 640;  }
    else if (layer == 3) { W = W3; S = S3; WZ = wz3; KW = 576;  KS = 64;  N = 128; kpad = 640;  }
    else                 { W = W4; S = S4; WZ = wz4; KW = 1152; KS = 128; N = 256; kpad = 1280; }
    if (t >= kpad * N) return;
    int k = t / N, n = t - k * N;
    float v = 0.0f;
    if (k < KW) v = W[(size_t)k * N + n];
    else if (k < KW + KS) v = S[(size_t)(k - KW) * N + n];
    WZ[t] = v;
}

// ---------------------------------------------------------------------------
// 2. FUSED kNN + basis (R11: top-2 cached selection). 4 waves/block.
// ---------------------------------------------------------------------------
__global__ __launch_bounds__(256) void knn_basis_kernel(
    const float* __restrict__ pts, const float* __restrict__ B_ff,
    const float* __restrict__ mlp_W, const float* __restrict__ permx,
    int* __restrict__ idx, float* __restrict__ P) {
    __shared__ float npt[4][KNN * 3];
    __shared__ float feats[4][7 * KNN];
    __shared__ float sc[4][64];
    __shared__ float zl[4][16];
    __shared__ float w[4][16];
    __shared__ int sIds[4][KNN];
    int tid = threadIdx.x;
    int wave = tid >> 6, lane = tid & 63;
    int bn_ = blockIdx.x * 4 + wave;
    int b = bn_ >> 10;

    // ---- kNN phase ----
    {
        double px = (double)pts[(size_t)bn_ * 3 + 0];
        double py = (double)pts[(size_t)bn_ * 3 + 1];
        double pz = (double)pts[(size_t)bn_ * 3 + 2];
        double xn = px * px + py * py + pz * pz;
        const float* pb = pts + (size_t)(b << 10) * 3;
        int base = lane * 16;
        double cand[16];
        #pragma unroll
        for (int j = 0; j < 16; j++) {
            int m = base + j;
            double qx = (double)pb[m * 3 + 0];
            double qy = (double)pb[m * 3 + 1];
            double qz = (double)pb[m * 3 + 2];
            double inner = px * qx + py * qy + pz * qz;
            double xm = qx * qx + qy * qy + qz * qz;
            cand[j] = 2.0 * inner - xn - xm;
        }
        double v1 = -DBL_BIG, v2 = -DBL_BIG;
        int i1 = 0x7fffffff, i2 = 0x7fffffff;
        #pragma unroll
        for (int j = 0; j < 16; j++) {
            double cv = cand[j]; int ci = base + j;
            if (cv > v1 || (cv == v1 && ci < i1)) {
                v2 = v1; i2 = i1; v1 = cv; i1 = ci;
            } else if (cv > v2 || (cv == v2 && ci < i2)) {
                v2 = cv; i2 = ci;
            }
        }
        unsigned alive = 0xFFFFu;
        bool have2 = true;
        int* op = idx + (size_t)bn_ * KNN;
        for (int it = 0; it < KNN; it++) {
            double bv = v1;
            int bi = i1;
            #pragma unroll
            for (int s = 1; s < 64; s <<= 1) {
                double ov = __shfl_xor(bv, s, 64);
                int oi = __shfl_xor(bi, s, 64);
                if (ov > bv || (ov == bv && oi < bi)) { bv = ov; bi = oi; }
            }
            if (lane == 0) op[it] = bi;
            if (lane == it) sIds[wave][it] = bi;
            bool iwin = ((bi >> 4) == lane);
            if (iwin) alive &= ~(1u << (bi & 15));
            if (iwin && have2) {
                v1 = v2; i1 = i2;
                have2 = false;
            } else if (iwin) {
                double a1 = -DBL_BIG, a2 = -DBL_BIG;
                int j1 = 0x7fffffff, j2 = 0x7fffffff;
                #pragma unroll
                for (int j = 0; j < 16; j++) {
                    bool al = (alive >> j) & 1u;
                    double cv = al ? cand[j] : -DBL_BIG;
                    int ci = al ? (base + j) : 0x7fffffff;
                    if (cv > a1 || (cv == a1 && ci < j1)) {
                        a2 = a1; j2 = j1; a1 = cv; j1 = ci;
                    } else if (cv > a2 || (cv == a2 && ci < j2)) {
                        a2 = cv; j2 = ci;
                    }
                }
                v1 = a1; i1 = j1; v2 = a2; i2 = j2;
                have2 = true;
            }
        }
    }
    __syncthreads();

    // ---- basis phase ----
    if (lane < KNN) {
        int m = sIds[wave][lane];
        const float* q = pts + ((size_t)(b << 10) + m) * 3;
        npt[wave][lane * 3 + 0] = q[0];
        npt[wave][lane * 3 + 1] = q[1];
        npt[wave][lane * 3 + 2] = q[2];
    }
    __syncthreads();
    if (lane < KNN) {
        float sx = npt[wave][0], sy = npt[wave][1], sz = npt[wave][2];
        float rx = npt[wave][lane * 3 + 0] - sx;
        float ry = npt[wave][lane * 3 + 1] - sy;
        float rz = npt[wave][lane * 3 + 2] - sz;
        float sq = rx * rx + ry * ry + rz * rz;
        float dist = (sq > 0.0f) ? sqrtf(sq) : 0.0f;
        feats[wave][lane * 7 + 0] = sx;
        feats[wave][lane * 7 + 1] = sy;
        feats[wave][lane * 7 + 2] = sz;
        feats[wave][lane * 7 + 3] = rx;
        feats[wave][lane * 7 + 4] = ry;
        feats[wave][lane * 7 + 5] = rz;
        feats[wave][lane * 7 + 6] = dist;
    }
    __syncthreads();
    {
        int j = lane & 31;
        int half = lane >> 5;
        int i0 = half * 105;
        float acc = 0.0f;
        for (int i = i0; i < i0 + 105; i++) acc += feats[wave][i] * B_ff[i * 32 + j];
        acc += __shfl_xor(acc, 32, 64);
        if (half == 0) {
            float ffv = 6.283185307179586f * acc;
            sc[wave][j] = sinf(ffv);
            sc[wave][j + 32] = cosf(ffv);
        }
    }
    __syncthreads();
    {
        int j = lane & 15;
        int h = lane >> 4;
        float acc = 0.0f;
        for (int i = 16 * h; i < 16 * h + 16; i++) acc += sc[wave][i] * mlp_W[i * 16 + j];
        acc += __shfl_xor(acc, 16, 64);
        acc += __shfl_xor(acc, 32, 64);
        if (h == 0) zl[wave][j] = acc;
    }
    __syncthreads();
    if (lane == 0) {
        float zs[16];
        for (int i = 0; i < 16; i++) zs[i] = zl[wave][i];
        for (int i = 1; i < 16; i++) {
            float key = zs[i]; int j = i - 1;
            while (j >= 0 && zs[j] < key) { zs[j + 1] = zs[j]; j--; }
            zs[j + 1] = key;
        }
        float cs = 0.0f, csarr[16];
        int cnt = 0;
        for (int j = 0; j < 16; j++) {
            cs += zs[j];
            csarr[j] = cs;
            if (1.0f + (float)(j + 1) * zs[j] > cs) cnt++;
        }
        float tau = (csarr[cnt - 1] - 1.0f) / (float)cnt;
        for (int i = 0; i < 16; i++) w[wave][i] = fmaxf(zl[wave][i] - tau, 0.0f);
    }
    __syncthreads();
    float* Pp = P + (size_t)bn_ * (KNN * TKR);
    for (int e = lane; e < KNN * TKR; e += 64) {
        int k = e / TKR, t = e - TKR * k;
        float acc = 0.0f;
        for (int i = 0; i < 16; i++) acc += w[wave][i] * permx[(i * KNN + k) * TKR + t];
        Pp[e] = acc;
    }
}

// ---------------------------------------------------------------------------
// 3a. agg (scalar, CIN=3 only)
// ---------------------------------------------------------------------------
template <int CIN>
__global__ __launch_bounds__(256) void agg_kernel(
    const float* __restrict__ ft, int ftst,
    const float* __restrict__ P, const int* __restrict__ idx,
    float* __restrict__ Z, int kpad) {
    __shared__ float sP[KNN * TKR];
    __shared__ float sNb[KNN * CIN];
    __shared__ int sIdx[KNN];
    int bn_ = blockIdx.x;
    int b = bn_ >> 10;
    int tid = threadIdx.x;
    if (tid < KNN) sIdx[tid] = idx[(size_t)bn_ * KNN + tid];
    for (int e = tid; e < KNN * TKR; e += 256) sP[e] = P[(size_t)bn_ * (KNN * TKR) + e];
    __syncthreads();
    for (int e = tid; e < KNN * CIN; e += 256) {
        int k = e / CIN, c = e - k * CIN;
        sNb[e] = ft[((size_t)(b << 10) + sIdx[k]) * ftst + c];
    }
    __syncthreads();
    float* zp = Z + (size_t)bn_ * kpad;
    const int KW = TKR * CIN;
    for (int e = tid; e < kpad; e += 256) {
        float v;
        if (e < KW) {
            int t = e / CIN, c = e - t * CIN;
            float acc = 0.0f;
            #pragma unroll
            for (int k = 0; k < KNN; k++) acc += sNb[k * CIN + c] * sP[k * TKR + t];
            v = acc;
        } else if (e < KW + CIN) {
            v = ft[(size_t)bn_ * ftst + (e - KW)];
        } else {
            v = 0.0f;
        }
        zp[e] = v;
    }
}

// ---------------------------------------------------------------------------
// 3b. agg vectorized (CIN in {64,128})
// ---------------------------------------------------------------------------
template <int CIN>
__global__ __launch_bounds__(256) void agg_v_kernel(
    const float* __restrict__ ft, int ftst,
    const float* __restrict__ P, const int* __restrict__ idx,
    float* __restrict__ Z, int kpad) {
    __shared__ float sP[KNN * TKR];
    __shared__ float sNb[KNN * CIN];
    __shared__ int sIdx[KNN];
    constexpr int C4 = CIN / 4;
    int bn_ = blockIdx.x;
    int b = bn_ >> 10;
    int tid = threadIdx.x;
    if (tid < KNN) sIdx[tid] = idx[(size_t)bn_ * KNN + tid];
    for (int e = tid; e < KNN * TKR; e += 256) sP[e] = P[(size_t)bn_ * (KNN * TKR) + e];
    __syncthreads();
    for (int e = tid; e < KNN * C4; e += 256) {
        int k = e / C4, c4 = (e - k * C4) * 4;
        *(float4*)&sNb[k * CIN + c4] =
            *(const float4*)&ft[((size_t)(b << 10) + sIdx[k]) * ftst + c4];
    }
    __syncthreads();
    float* zp = Z + (size_t)bn_ * kpad;
    const int KW = TKR * CIN;
    for (int e = tid; e < (kpad >> 2); e += 256) {
        int c0 = e * 4;
        float4 v;
        if (c0 < KW) {
            int t = c0 / CIN, c4 = c0 - t * CIN;
            float4 a = make_float4(0.f, 0.f, 0.f, 0.f);
            #pragma unroll
            for (int k = 0; k < KNN; k++) {
                float p = sP[k * TKR + t];
                float4 nb = *(const float4*)&sNb[k * CIN + c4];
                a.x += nb.x * p; a.y += nb.y * p;
                a.z += nb.z * p; a.w += nb.w * p;
            }
            v = a;
        } else if (c0 < KW + CIN) {
            v = *(const float4*)&ft[(size_t)bn_ * ftst + (c0 - KW)];
        } else {
            v = make_float4(0.f, 0.f, 0.f, 0.f);
        }
        *(float4*)&zp[c0] = v;
    }
}

// ---------------------------------------------------------------------------
// 4. 64x64 GEMM, LDS double-buffered + reg prefetch (proven R7). L1-L3.
// ---------------------------------------------------------------------------
template <bool GELU, bool HASBIAS>
__global__ __launch_bounds__(256) void gemm_f32_64db(
    const float* __restrict__ A, int lda,
    const float* __restrict__ B, int ldb, int K,
    const float* __restrict__ bias,
    float* __restrict__ C, int ldc) {
    __shared__ float As[2][16][64];
    __shared__ float Bs[2][16][64];
    int tid = threadIdx.x;
    int tx = tid & 15, ty = tid >> 4;
    int m0 = blockIdx.y * 64, n0 = blockIdx.x * 64;
    float acc[4][4];
    #pragma unroll
    for (int i = 0; i < 4; i++)
        #pragma unroll
        for (int j = 0; j < 4; j++) acc[i][j] = 0.0f;

    int ar = tid >> 2, ac0 = (tid & 3) * 4;
    const float* aptr = A + (size_t)(m0 + ar) * lda + ac0;
    int br = tid >> 4, bc = (tid & 15) * 4;
    const float* bptr = B + (size_t)br * ldb + n0 + bc;

    float4 pa = *(const float4*)(aptr);
    float4 pb = *(const float4*)(bptr);
    As[0][ac0 + 0][ar] = pa.x; As[0][ac0 + 1][ar] = pa.y;
    As[0][ac0 + 2][ar] = pa.z; As[0][ac0 + 3][ar] = pa.w;
    *(float4*)&Bs[0][br][bc] = pb;
    __syncthreads();

    int nk = K >> 4;
    for (int t = 0; t < nk; t++) {
        int buf = t & 1;
        bool more = (t + 1) < nk;
        if (more) {
            int k0 = (t + 1) << 4;
            pa = *(const float4*)(aptr + k0);
            pb = *(const float4*)(bptr + (size_t)k0 * ldb);
        }
        #pragma unroll
        for (int kk = 0; kk < 16; kk++) {
            float av[4], bv[4];
            *(float4*)&av[0] = *(const float4*)&As[buf][kk][ty * 4];
            *(float4*)&bv[0] = *(const float4*)&Bs[buf][kk][tx * 4];
            #pragma unroll
            for (int i = 0; i < 4; i++)
                #pragma unroll
                for (int j = 0; j < 4; j++) acc[i][j] += av[i] * bv[j];
        }
        if (more) {
            int nb = 1 - buf;
            As[nb][ac0 + 0][ar] = pa.x; As[nb][ac0 + 1][ar] = pa.y;
            As[nb][ac0 + 2][ar] = pa.z; As[nb][ac0 + 3][ar] = pa.w;
            *(float4*)&Bs[nb][br][bc] = pb;
        }
        __syncthreads();
    }
    #pragma unroll
    for (int i = 0; i < 4; i++) {
        int r = m0 + ty * 4 + i;
        int c = n0 + tx * 4;
        float v[4];
        #pragma unroll
        for (int j = 0; j < 4; j++) {
            float t = acc[i][j];
            if (HASBIAS) t += bias[c + j];
            if (GELU) t = gelu_f(t);
            v[j] = t;
        }
        *(float4*)(C + (size_t)r * ldc + c) = *(float4*)v;
    }
}

// ---------------------------------------------------------------------------
// 5. 64x128 GEMM, LDS double-buffered + reg prefetch. Better latency hiding
//    than the 128x128 2-barrier conv5 shape (24 KB LDS -> ~6 blocks/CU vs 2;
//    R6 lesson: keep VGPR under the 128 cliff — acc 32 + prefetch 12 ~ 72).
//    Optional fused BN column partials (64-row m-blocks). Per-output k-order
//    identical to previous kernels (bit-exact C).
// ---------------------------------------------------------------------------
template <bool GELU, bool HASBIAS, bool STATS>
__global__ __launch_bounds__(256) void gemm_f32_64x128(
    const float* __restrict__ A, int lda,
    const float* __restrict__ B, int ldb, int K,
    const float* __restrict__ bias,
    float* __restrict__ C, int ldc,
    float* __restrict__ partS, float* __restrict__ partQ) {
    __shared__ float As[2][16][64];    // 8 KB
    __shared__ float Bs[2][16][128];   // 16 KB
    int tid = threadIdx.x;
    int tx = tid & 15, ty = tid >> 4;
    int m0 = blockIdx.y * 64, n0 = blockIdx.x * 128;
    float acc[4][8];
    #pragma unroll
    for (int i = 0; i < 4; i++)
        #pragma unroll
        for (int j = 0; j < 8; j++) acc[i][j] = 0.0f;

    int ar = tid >> 2, ac0 = (tid & 3) * 4;
    const float* aptr = A + (size_t)(m0 + ar) * lda + ac0;
    int br = tid >> 5, bc = (tid & 31) * 4;
    const float* bptr = B + (size_t)br * ldb + n0 + bc;

    float4 pa = *(const float4*)(aptr);
    float4 pb0 = *(const float4*)(bptr);
    float4 pb1 = *(const float4*)(bptr + (size_t)8 * ldb);
    As[0][ac0 + 0][ar] = pa.x; As[0][ac0 + 1][ar] = pa.y;
    As[0][ac0 + 2][ar] = pa.z; As[0][ac0 + 3][ar] = pa.w;
    *(float4*)&Bs[0][br][bc] = pb0;
    *(float4*)&Bs[0][br + 8][bc] = pb1;
    __syncthreads();

    int nk = K >> 4;
    for (int t = 0; t < nk; t++) {
        int buf = t & 1;
        bool more = (t + 1) < nk;
        if (more) {
            int k0 = (t + 1) << 4;
            pa = *(const float4*)(aptr + k0);
            pb0 = *(const float4*)(bptr + (size_t)k0 * ldb);
            pb1 = *(const float4*)(bptr + (size_t)(k0 + 8) * ldb);
        }
        #pragma unroll
        for (int kk = 0; kk < 16; kk++) {
            float av[4], bv[8];
            *(float4*)&av[0] = *(const float4*)&As[buf][kk][ty * 4];
            *(float4*)&bv[0] = *(const float4*)&Bs[buf][kk][tx * 4];
            *(float4*)&bv[4] = *(const float4*)&Bs[buf][kk][64 + tx * 4];
            #pragma unroll
            for (int i = 0; i < 4; i++)
                #pragma unroll
                for (int j = 0; j < 8; j++) acc[i][j] += av[i] * bv[j];
        }
        if (more) {
            int nb = 1 - buf;
            As[nb][ac0 + 0][ar] = pa.x; As[nb][ac0 + 1][ar] = pa.y;
            As[nb][ac0 + 2][ar] = pa.z; As[nb][ac0 + 3][ar] = pa.w;
            *(float4*)&Bs[nb][br][bc] = pb0;
            *(float4*)&Bs[nb][br + 8][bc] = pb1;
        }
        __syncthreads();
    }
    #pragma unroll
    for (int i = 0; i < 4; i++) {
        int r = m0 + ty * 4 + i;
        #pragma unroll
        for (int hj = 0; hj < 2; hj++) {
            int c = n0 + hj * 64 + tx * 4;
            float v[4];
            #pragma unroll
            for (int j = 0; j < 4; j++) {
                float t = acc[i][hj * 4 + j];
                if (HASBIAS) t += bias[c + j];
                if (GELU) t = gelu_f(t);
                v[j] = t;
            }
            *(float4*)(C + (size_t)r * ldc + c) = *(float4*)v;
        }
    }
    if (STATS) {
        // per-block BN column partials over this block's 64 rows.
        // LDS reuse safe: final loop iter ended with __syncthreads.
        float* sS = &As[0][0][0];   // 2048 floats needed (16 ty x 128 col)
        float* sQ = &Bs[0][0][0];
        #pragma unroll
        for (int hj = 0; hj < 2; hj++) {
            #pragma unroll
            for (int j = 0; j < 4; j++) {
                int cl = hj * 64 + tx * 4 + j;
                float s = 0.0f, q = 0.0f;
                #pragma unroll
                for (int i = 0; i < 4; i++) {
                    float v = acc[i][hj * 4 + j];
                    s += v; q += v * v;
                }
                sS[ty * 128 + cl] = s;
                sQ[ty * 128 + cl] = q;
            }
        }
        __syncthreads();
        if (tid < 128) {
            float S = 0.0f, Q = 0.0f;
            #pragma unroll
            for (int tt = 0; tt < 16; tt++) {
                S += sS[tt * 128 + tid];
                Q += sQ[tt * 128 + tid];
            }
            partS[(size_t)blockIdx.y * 1024 + n0 + tid] = S;
            partQ[(size_t)blockIdx.y * 1024 + n0 + tid] = Q;
        }
    }
}

// ---------------------------------------------------------------------------
// 6. stats_reduce over 256 per-m-block partials (deterministic order)
// ---------------------------------------------------------------------------
__global__ __launch_bounds__(256) void stats_reduce(
    const float* __restrict__ partS, const float* __restrict__ partQ,
    const float* __restrict__ g, const float* __restrict__ be,
    float* __restrict__ scaleb, float* __restrict__ shiftb) {
    int e = blockIdx.x * 256 + threadIdx.x;
    if (e >= 1024) return;
    double s = 0.0, q = 0.0;
    for (int mb = 0; mb < 256; mb++) {
        s += (double)partS[(size_t)mb * 1024 + e];
        q += (double)partQ[(size_t)mb * 1024 + e];
    }
    double m = s * (1.0 / 16384.0);
    double v = q * (1.0 / 16384.0) - m * m;
    float sc = g[e] * (float)(1.0 / sqrt(v + 1e-5));
    scaleb[e] = sc;
    shiftb[e] = be[e] - (float)m * sc;
}

// ---------------------------------------------------------------------------
// 7. pool
// ---------------------------------------------------------------------------
__global__ __launch_bounds__(256) void pool_kernel(
    const float* __restrict__ f5, const float* __restrict__ scaleb,
    const float* __restrict__ shiftb, float* __restrict__ h) {
    int b = blockIdx.x >> 4;
    int g = blockIdx.x & 15;
    int e = g * 64 + (threadIdx.x & 63);
    int nlane = threadIdx.x >> 6;
    float sc = scaleb[e], sh = shiftb[e];
    float vmax = -FLT_BIG;
    double vsum = 0.0;
    for (int n = nlane; n < NPT; n += 4) {
        float v = f5[((size_t)b * NPT + n) * 1024 + e];
        v = gelu_f(v * sc + sh);
        vmax = fmaxf(vmax, v);
        vsum += (double)v;
    }
    __shared__ float smax[256];
    __shared__ double ssum[256];
    smax[threadIdx.x] = vmax;
    ssum[threadIdx.x] = vsum;
    __syncthreads();
    if (nlane == 0) {
        for (int i = 1; i < 4; i++) {
            vmax = fmaxf(vmax, smax[threadIdx.x + 64 * i]);
            vsum += ssum[threadIdx.x + 64 * i];
        }
        h[(size_t)b * 2048 + e] = vmax;
        h[(size_t)b * 2048 + 1024 + e] = (float)(vsum * (1.0 / 1024.0));
    }
}

// ---------------------------------------------------------------------------
// 8. FC head: split-K fp64 partials; fused reduce+BN+gelu.
// ---------------------------------------------------------------------------
__global__ __launch_bounds__(256) void fc_split(
    const float* __restrict__ X, const float* __restrict__ W,
    double* __restrict__ part, int Bn, int In, int Out, int KC) {
    int tid = blockIdx.x * 256 + threadIdx.x;
    if (tid >= Bn * Out * KC) return;
    int chunk = tid / (Bn * Out);
    int r = tid - chunk * (Bn * Out);
    int b = r / Out, j = r - b * Out;
    int len = In / KC;
    int i0 = chunk * len;
    const float* x = X + (size_t)b * In + i0;
    const float* w = W + (size_t)i0 * Out + j;
    double acc = 0.0;
    for (int i = 0; i < len; i++) acc += (double)x[i] * (double)w[(size_t)i * Out];
    part[tid] = acc;
}

__global__ __launch_bounds__(256) void fc_bn_gelu(
    const double* __restrict__ part, const float* __restrict__ bias,
    const float* __restrict__ g, const float* __restrict__ be,
    float* __restrict__ Y, int Out, int KC) {
    int j = blockIdx.x * 256 + threadIdx.x;
    if (j >= Out) return;
    float r[BSZ];
    for (int b = 0; b < BSZ; b++) {
        double acc = bias ? (double)bias[j] : 0.0;
        for (int c = 0; c < KC; c++) acc += part[(size_t)c * (BSZ * Out) + b * Out + j];
        r[b] = (float)acc;
    }
    double m = 0.0;
    for (int b = 0; b < BSZ; b++) m += (double)r[b];
    m /= (double)BSZ;
    double v = 0.0;
    for (int b = 0; b < BSZ; b++) {
        double dd = (double)r[b] - m;
        v += dd * dd;
    }
    v /= (double)BSZ;
    float sc = g[j] * (float)(1.0 / sqrt(v + 1e-5));
    float sh = be[j] - (float)m * sc;
    for (int b = 0; b < BSZ; b++) Y[b * Out + j] = gelu_f(r[b] * sc + sh);
}

__global__ __launch_bounds__(256) void fc_reduce(
    const double* __restrict__ part, const float* __restrict__ bias,
    float* __restrict__ Y, int Bn, int Out, int KC) {
    int r = blockIdx.x * 256 + threadIdx.x;
    if (r >= Bn * Out) return;
    int j = r % Out;
    double acc = bias ? (double)bias[j] : 0.0;
    for (int c = 0; c < KC; c++) acc += part[(size_t)c * (Bn * Out) + r];
    Y[r] = (float)acc;
}

// ---------------------------------------------------------------------------
extern "C" void kernel_launch(void* const* d_in, const int* in_sizes, int n_in,
                              void* d_out, int out_size, void* d_ws, size_t ws_size,
                              hipStream_t stream) {
    const float* x     = (const float*)d_in[0];
    const float* B_ff  = (const float*)d_in[1];
    const float* mlp_W = (const float*)d_in[2];
    const float* permx = (const float*)d_in[3];
    const float* W1 = (const float*)d_in[4];
    const float* b1 = (const float*)d_in[5];
    const float* S1 = (const float*)d_in[6];
    const float* W2 = (const float*)d_in[7];
    const float* b2 = (const float*)d_in[8];
    const float* S2 = (const float*)d_in[9];
    const float* W3 = (const float*)d_in[10];
    const float* b3 = (const float*)d_in[11];
    const float* S3 = (const float*)d_in[12];
    const float* W4 = (const float*)d_in[13];
    const float* b4 = (const float*)d_in[14];
    const float* S4 = (const float*)d_in[15];
    const float* W5 = (const float*)d_in[16];
    const float* g5 = (const float*)d_in[17];
    const float* be5 = (const float*)d_in[18];
    const float* L1 = (const float*)d_in[19];
    const float* g6 = (const float*)d_in[20];
    const float* be6 = (const float*)d_in[21];
    const float* L2 = (const float*)d_in[22];
    const float* bL2 = (const float*)d_in[23];
    const float* g7 = (const float*)d_in[24];
    const float* be7 = (const float*)d_in[25];
    const float* L3 = (const float*)d_in[26];
    const float* bL3 = (const float*)d_in[27];
    float* outp = (float*)d_out;

    const int BN = BSZ * NPT;  // 16384

    // workspace (float units; 16B-aligned). Liveness-based unions (R9/R11):
    //   f5 aliases Zbig; wz1..wz3 in Zbig tail beyond the L1-L3 Z extent;
    //   wz4 own slot; partC_S/Q (now 256x1024 each) + partF alias Pb
    //   (dead after L4 agg; 256K+256K+256K floats < Pb's 4.4M).
    float* ws = (float*)d_ws;
    float* pts   = ws;                         // 49152
    int*   idxb  = (int*)(ws + 49152);         // 491520 ints
    float* Pb    = ws + 540672;                // 4423680
    float* feat  = Pb + 4423680;               // 8388608 (x1|x2|x3|x4, stride 512)
    float* Zbig  = feat + 8388608;             // 20971520 (max layer: 16384x1280)
    float* f5    = Zbig;                       // union: 16777216
    float* wz4   = Zbig + 20971520;            // 327680
    float* scb   = wz4 + 327680;               // 1024
    float* shb   = scb + 1024;                 // 1024
    float* hb    = shb + 1024;                 // 32768
    float* y1    = hb + 32768;                 // 8192
    float* y2    = y1 + 8192;                  // 4096
    float* wz1   = Zbig + 11010048;            // 2048   (Zbig tail, dead by L4 agg)
    float* wz2   = wz1 + 2048;                 // 40960
    float* wz3   = wz2 + 40960;                // 81920  (ends 11134976 < 16777216)
    float* partC_S = Pb;                       // 262144 (256 m-blocks x 1024)
    float* partC_Q = Pb + 262144;              // 262144
    double* partF  = (double*)(Pb + 524288);   // 131072 doubles
    size_t need_bytes = (size_t)((y2 + 4096) - ws) * sizeof(float);
    if (ws_size < need_bytes) return;

    // setup: transpose + all 4 WZ preps in one dispatch
    prep_all<<<dim3(1280, 5), 256, 0, stream>>>(
        x, pts, W1, S1, wz1, W2, S2, wz2, W3, S3, wz3, W4, S4, wz4);

    // fused kNN + basis (R11: top-2 cached selection)
    knn_basis_kernel<<<BN / 4, 256, 0, stream>>>(pts, B_ff, mlp_W, permx, idxb, Pb);

    // ---- layer 1: CIN=3, kpad=32, N=64 ----
    agg_kernel<3><<<BN, 256, 0, stream>>>(pts, 3, Pb, idxb, Zbig, 32);
    gemm_f32_64db<true, true><<<dim3(1, 256), 256, 0, stream>>>(
        Zbig, 32, wz1, 64, 32, b1, feat + 0, 512);
    // ---- layer 2: CIN=64, kpad=640, N=64 ----
    agg_v_kernel<64><<<BN, 256, 0, stream>>>(feat + 0, 512, Pb, idxb, Zbig, 640);
    gemm_f32_64db<true, true><<<dim3(1, 256), 256, 0, stream>>>(
        Zbig, 640, wz2, 64, 640, b2, feat + 64, 512);
    // ---- layer 3: CIN=64, kpad=640, N=128 ----
    agg_v_kernel<64><<<BN, 256, 0, stream>>>(feat + 64, 512, Pb, idxb, Zbig, 640);
    gemm_f32_64db<true, true><<<dim3(2, 256), 256, 0, stream>>>(
        Zbig, 640, wz3, 128, 640, b3, feat + 128, 512);
    // ---- layer 4: CIN=128, kpad=1280, N=256 -> 64x128 tile (512 blocks) ----
    agg_v_kernel<128><<<BN, 256, 0, stream>>>(feat + 128, 512, Pb, idxb, Zbig, 1280);
    gemm_f32_64x128<true, true, false><<<dim3(2, 256), 256, 0, stream>>>(
        Zbig, 1280, wz4, 256, 1280, b4, feat + 256, 512, nullptr, nullptr);

    // ---- conv5 + fused BN partials: 64x128 tile (2048 blocks, ~6/CU) ----
    gemm_f32_64x128<false, false, true><<<dim3(8, 256), 256, 0, stream>>>(
        feat, 512, W5, 1024, 512, nullptr, f5, 1024, partC_S, partC_Q);

    stats_reduce<<<4, 256, 0, stream>>>(partC_S, partC_Q, g5, be5, scb, shb);
    pool_kernel<<<BSZ * 16, 256, 0, stream>>>(f5, scb, shb, hb);

    // ---- FC head ----
    fc_split<<<(BSZ * 512 * 16 + 255) / 256, 256, 0, stream>>>(hb, L1, partF, BSZ, 2048, 512, 16);
    fc_bn_gelu<<<2, 256, 0, stream>>>(partF, nullptr, g6, be6, y1, 512, 16);
    fc_split<<<(BSZ * 256 * 8 + 255) / 256, 256, 0, stream>>>(y1, L2, partF, BSZ, 512, 256, 8);
    fc_bn_gelu<<<1, 256, 0, stream>>>(partF, bL2, g7, be7, y2, 256, 8);
    fc_split<<<(BSZ * 40 * 4 + 255) / 256, 256, 0, stream>>>(y2, L3, partF, BSZ, 256, 40, 4);
    fc_reduce<<<(BSZ * 40 + 255) / 256, 256, 0, stream>>>(partF, bL3, outp, BSZ, 40, 4);
}

// Round 13
// 1114.725 us; speedup vs baseline: 1.0430x; 1.0430x over previous
//
#include <hip/hip_runtime.h>
#include <hip/hip_bf16.h>
#include <cstddef>

#define BSZ 16
#define NPT 1024
#define KNN 30
#define TKR 9
#define FLT_BIG 3.402823466e+38f
#define DBL_BIG 1.0e300

__device__ __forceinline__ float gelu_f(float x) {
    return 0.5f * x * (1.0f + erff(x * 0.7071067811865476f));
}

// ---------------------------------------------------------------------------
// 1. prep_all: layer 0 = transpose x; layers 1..4 = WZ_l = [W;S;pad]
// ---------------------------------------------------------------------------
__global__ __launch_bounds__(256) void prep_all(
    const float* __restrict__ x, float* __restrict__ pts,
    const float* __restrict__ W1, const float* __restrict__ S1, float* __restrict__ wz1,
    const float* __restrict__ W2, const float* __restrict__ S2, float* __restrict__ wz2,
    const float* __restrict__ W3, const float* __restrict__ S3, float* __restrict__ wz3,
    const float* __restrict__ W4, const float* __restrict__ S4, float* __restrict__ wz4) {
    int layer = blockIdx.y;
    int t = blockIdx.x * 256 + threadIdx.x;
    if (layer == 0) {
        if (t >= BSZ * NPT) return;
        int b = t >> 10, n = t & 1023;
        const float* xp = x + (size_t)b * 3 * NPT;
        pts[t * 3 + 0] = xp[n];
        pts[t * 3 + 1] = xp[NPT + n];
        pts[t * 3 + 2] = xp[2 * NPT + n];
        return;
    }
    const float *W, *S; float* WZ; int KW, KS, N, kpad;
    if (layer == 1)      { W = W1; S = S1; WZ = wz1; KW = 27;   KS = 3;   N = 64;  kpad = 32;   }
    else if (layer == 2) { W = W2; S = S2; WZ = wz2; KW = 576;  KS = 64;  N = 64;  kpad = 640;  }
    else if (layer == 3) { W = W3; S = S3; WZ = wz3; KW = 576;  KS = 64;  N = 128; kpad = 640;  }
    else                 { W = W4; S = S4; WZ = wz4; KW = 1152; KS = 128; N = 256; kpad = 1280; }
    if (t >= kpad * N) return;
    int k = t / N, n = t - k * N;
    float v = 0.0f;
    if (k < KW) v = W[(size_t)k * N + n];
    else if (k < KW + KS) v = S[(size_t)(k - KW) * N + n];
    WZ[t] = v;
}

// ---------------------------------------------------------------------------
// 2. FUSED kNN + basis (R11: top-2 cached selection). 4 waves/block.
// ---------------------------------------------------------------------------
__global__ __launch_bounds__(256) void knn_basis_kernel(
    const float* __restrict__ pts, const float* __restrict__ B_ff,
    const float* __restrict__ mlp_W, const float* __restrict__ permx,
    int* __restrict__ idx, float* __restrict__ P) {
    __shared__ float npt[4][KNN * 3];
    __shared__ float feats[4][7 * KNN];
    __shared__ float sc[4][64];
    __shared__ float zl[4][16];
    __shared__ float w[4][16];
    __shared__ int sIds[4][KNN];
    int tid = threadIdx.x;
    int wave = tid >> 6, lane = tid & 63;
    int bn_ = blockIdx.x * 4 + wave;
    int b = bn_ >> 10;

    // ---- kNN phase ----
    {
        double px = (double)pts[(size_t)bn_ * 3 + 0];
        double py = (double)pts[(size_t)bn_ * 3 + 1];
        double pz = (double)pts[(size_t)bn_ * 3 + 2];
        double xn = px * px + py * py + pz * pz;
        const float* pb = pts + (size_t)(b << 10) * 3;
        int base = lane * 16;
        double cand[16];
        #pragma unroll
        for (int j = 0; j < 16; j++) {
            int m = base + j;
            double qx = (double)pb[m * 3 + 0];
            double qy = (double)pb[m * 3 + 1];
            double qz = (double)pb[m * 3 + 2];
            double inner = px * qx + py * qy + pz * qz;
            double xm = qx * qx + qy * qy + qz * qz;
            cand[j] = 2.0 * inner - xn - xm;
        }
        double v1 = -DBL_BIG, v2 = -DBL_BIG;
        int i1 = 0x7fffffff, i2 = 0x7fffffff;
        #pragma unroll
        for (int j = 0; j < 16; j++) {
            double cv = cand[j]; int ci = base + j;
            if (cv > v1 || (cv == v1 && ci < i1)) {
                v2 = v1; i2 = i1; v1 = cv; i1 = ci;
            } else if (cv > v2 || (cv == v2 && ci < i2)) {
                v2 = cv; i2 = ci;
            }
        }
        unsigned alive = 0xFFFFu;
        bool have2 = true;
        int* op = idx + (size_t)bn_ * KNN;
        for (int it = 0; it < KNN; it++) {
            double bv = v1;
            int bi = i1;
            #pragma unroll
            for (int s = 1; s < 64; s <<= 1) {
                double ov = __shfl_xor(bv, s, 64);
                int oi = __shfl_xor(bi, s, 64);
                if (ov > bv || (ov == bv && oi < bi)) { bv = ov; bi = oi; }
            }
            if (lane == 0) op[it] = bi;
            if (lane == it) sIds[wave][it] = bi;
            bool iwin = ((bi >> 4) == lane);
            if (iwin) alive &= ~(1u << (bi & 15));
            if (iwin && have2) {
                v1 = v2; i1 = i2;
                have2 = false;
            } else if (iwin) {
                double a1 = -DBL_BIG, a2 = -DBL_BIG;
                int j1 = 0x7fffffff, j2 = 0x7fffffff;
                #pragma unroll
                for (int j = 0; j < 16; j++) {
                    bool al = (alive >> j) & 1u;
                    double cv = al ? cand[j] : -DBL_BIG;
                    int ci = al ? (base + j) : 0x7fffffff;
                    if (cv > a1 || (cv == a1 && ci < j1)) {
                        a2 = a1; j2 = j1; a1 = cv; j1 = ci;
                    } else if (cv > a2 || (cv == a2 && ci < j2)) {
                        a2 = cv; j2 = ci;
                    }
                }
                v1 = a1; i1 = j1; v2 = a2; i2 = j2;
                have2 = true;
            }
        }
    }
    __syncthreads();

    // ---- basis phase ----
    if (lane < KNN) {
        int m = sIds[wave][lane];
        const float* q = pts + ((size_t)(b << 10) + m) * 3;
        npt[wave][lane * 3 + 0] = q[0];
        npt[wave][lane * 3 + 1] = q[1];
        npt[wave][lane * 3 + 2] = q[2];
    }
    __syncthreads();
    if (lane < KNN) {
        float sx = npt[wave][0], sy = npt[wave][1], sz = npt[wave][2];
        float rx = npt[wave][lane * 3 + 0] - sx;
        float ry = npt[wave][lane * 3 + 1] - sy;
        float rz = npt[wave][lane * 3 + 2] - sz;
        float sq = rx * rx + ry * ry + rz * rz;
        float dist = (sq > 0.0f) ? sqrtf(sq) : 0.0f;
        feats[wave][lane * 7 + 0] = sx;
        feats[wave][lane * 7 + 1] = sy;
        feats[wave][lane * 7 + 2] = sz;
        feats[wave][lane * 7 + 3] = rx;
        feats[wave][lane * 7 + 4] = ry;
        feats[wave][lane * 7 + 5] = rz;
        feats[wave][lane * 7 + 6] = dist;
    }
    __syncthreads();
    {
        int j = lane & 31;
        int half = lane >> 5;
        int i0 = half * 105;
        float acc = 0.0f;
        for (int i = i0; i < i0 + 105; i++) acc += feats[wave][i] * B_ff[i * 32 + j];
        acc += __shfl_xor(acc, 32, 64);
        if (half == 0) {
            float ffv = 6.283185307179586f * acc;
            sc[wave][j] = sinf(ffv);
            sc[wave][j + 32] = cosf(ffv);
        }
    }
    __syncthreads();
    {
        int j = lane & 15;
        int h = lane >> 4;
        float acc = 0.0f;
        for (int i = 16 * h; i < 16 * h + 16; i++) acc += sc[wave][i] * mlp_W[i * 16 + j];
        acc += __shfl_xor(acc, 16, 64);
        acc += __shfl_xor(acc, 32, 64);
        if (h == 0) zl[wave][j] = acc;
    }
    __syncthreads();
    if (lane == 0) {
        float zs[16];
        for (int i = 0; i < 16; i++) zs[i] = zl[wave][i];
        for (int i = 1; i < 16; i++) {
            float key = zs[i]; int j = i - 1;
            while (j >= 0 && zs[j] < key) { zs[j + 1] = zs[j]; j--; }
            zs[j + 1] = key;
        }
        float cs = 0.0f, csarr[16];
        int cnt = 0;
        for (int j = 0; j < 16; j++) {
            cs += zs[j];
            csarr[j] = cs;
            if (1.0f + (float)(j + 1) * zs[j] > cs) cnt++;
        }
        float tau = (csarr[cnt - 1] - 1.0f) / (float)cnt;
        for (int i = 0; i < 16; i++) w[wave][i] = fmaxf(zl[wave][i] - tau, 0.0f);
    }
    __syncthreads();
    float* Pp = P + (size_t)bn_ * (KNN * TKR);
    for (int e = lane; e < KNN * TKR; e += 64) {
        int k = e / TKR, t = e - TKR * k;
        float acc = 0.0f;
        for (int i = 0; i < 16; i++) acc += w[wave][i] * permx[(i * KNN + k) * TKR + t];
        Pp[e] = acc;
    }
}

// ---------------------------------------------------------------------------
// 3a. agg (scalar, CIN=3 only)
// ---------------------------------------------------------------------------
template <int CIN>
__global__ __launch_bounds__(256) void agg_kernel(
    const float* __restrict__ ft, int ftst,
    const float* __restrict__ P, const int* __restrict__ idx,
    float* __restrict__ Z, int kpad) {
    __shared__ float sP[KNN * TKR];
    __shared__ float sNb[KNN * CIN];
    __shared__ int sIdx[KNN];
    int bn_ = blockIdx.x;
    int b = bn_ >> 10;
    int tid = threadIdx.x;
    if (tid < KNN) sIdx[tid] = idx[(size_t)bn_ * KNN + tid];
    for (int e = tid; e < KNN * TKR; e += 256) sP[e] = P[(size_t)bn_ * (KNN * TKR) + e];
    __syncthreads();
    for (int e = tid; e < KNN * CIN; e += 256) {
        int k = e / CIN, c = e - k * CIN;
        sNb[e] = ft[((size_t)(b << 10) + sIdx[k]) * ftst + c];
    }
    __syncthreads();
    float* zp = Z + (size_t)bn_ * kpad;
    const int KW = TKR * CIN;
    for (int e = tid; e < kpad; e += 256) {
        float v;
        if (e < KW) {
            int t = e / CIN, c = e - t * CIN;
            float acc = 0.0f;
            #pragma unroll
            for (int k = 0; k < KNN; k++) acc += sNb[k * CIN + c] * sP[k * TKR + t];
            v = acc;
        } else if (e < KW + CIN) {
            v = ft[(size_t)bn_ * ftst + (e - KW)];
        } else {
            v = 0.0f;
        }
        zp[e] = v;
    }
}

// ---------------------------------------------------------------------------
// 3b. agg vectorized (CIN in {64,128})
// ---------------------------------------------------------------------------
template <int CIN>
__global__ __launch_bounds__(256) void agg_v_kernel(
    const float* __restrict__ ft, int ftst,
    const float* __restrict__ P, const int* __restrict__ idx,
    float* __restrict__ Z, int kpad) {
    __shared__ float sP[KNN * TKR];
    __shared__ float sNb[KNN * CIN];
    __shared__ int sIdx[KNN];
    constexpr int C4 = CIN / 4;
    int bn_ = blockIdx.x;
    int b = bn_ >> 10;
    int tid = threadIdx.x;
    if (tid < KNN) sIdx[tid] = idx[(size_t)bn_ * KNN + tid];
    for (int e = tid; e < KNN * TKR; e += 256) sP[e] = P[(size_t)bn_ * (KNN * TKR) + e];
    __syncthreads();
    for (int e = tid; e < KNN * C4; e += 256) {
        int k = e / C4, c4 = (e - k * C4) * 4;
        *(float4*)&sNb[k * CIN + c4] =
            *(const float4*)&ft[((size_t)(b << 10) + sIdx[k]) * ftst + c4];
    }
    __syncthreads();
    float* zp = Z + (size_t)bn_ * kpad;
    const int KW = TKR * CIN;
    for (int e = tid; e < (kpad >> 2); e += 256) {
        int c0 = e * 4;
        float4 v;
        if (c0 < KW) {
            int t = c0 / CIN, c4 = c0 - t * CIN;
            float4 a = make_float4(0.f, 0.f, 0.f, 0.f);
            #pragma unroll
            for (int k = 0; k < KNN; k++) {
                float p = sP[k * TKR + t];
                float4 nb = *(const float4*)&sNb[k * CIN + c4];
                a.x += nb.x * p; a.y += nb.y * p;
                a.z += nb.z * p; a.w += nb.w * p;
            }
            v = a;
        } else if (c0 < KW + CIN) {
            v = *(const float4*)&ft[(size_t)bn_ * ftst + (c0 - KW)];
        } else {
            v = make_float4(0.f, 0.f, 0.f, 0.f);
        }
        *(float4*)&zp[c0] = v;
    }
}

// ---------------------------------------------------------------------------
// 4. 64x64 GEMM, LDS double-buffered + reg prefetch (proven R7). L1-L3.
// ---------------------------------------------------------------------------
template <bool GELU, bool HASBIAS>
__global__ __launch_bounds__(256) void gemm_f32_64db(
    const float* __restrict__ A, int lda,
    const float* __restrict__ B, int ldb, int K,
    const float* __restrict__ bias,
    float* __restrict__ C, int ldc) {
    __shared__ float As[2][16][64];
    __shared__ float Bs[2][16][64];
    int tid = threadIdx.x;
    int tx = tid & 15, ty = tid >> 4;
    int m0 = blockIdx.y * 64, n0 = blockIdx.x * 64;
    float acc[4][4];
    #pragma unroll
    for (int i = 0; i < 4; i++)
        #pragma unroll
        for (int j = 0; j < 4; j++) acc[i][j] = 0.0f;

    int ar = tid >> 2, ac0 = (tid & 3) * 4;
    const float* aptr = A + (size_t)(m0 + ar) * lda + ac0;
    int br = tid >> 4, bc = (tid & 15) * 4;
    const float* bptr = B + (size_t)br * ldb + n0 + bc;

    float4 pa = *(const float4*)(aptr);
    float4 pb = *(const float4*)(bptr);
    As[0][ac0 + 0][ar] = pa.x; As[0][ac0 + 1][ar] = pa.y;
    As[0][ac0 + 2][ar] = pa.z; As[0][ac0 + 3][ar] = pa.w;
    *(float4*)&Bs[0][br][bc] = pb;
    __syncthreads();

    int nk = K >> 4;
    for (int t = 0; t < nk; t++) {
        int buf = t & 1;
        bool more = (t + 1) < nk;
        if (more) {
            int k0 = (t + 1) << 4;
            pa = *(const float4*)(aptr + k0);
            pb = *(const float4*)(bptr + (size_t)k0 * ldb);
        }
        #pragma unroll
        for (int kk = 0; kk < 16; kk++) {
            float av[4], bv[4];
            *(float4*)&av[0] = *(const float4*)&As[buf][kk][ty * 4];
            *(float4*)&bv[0] = *(const float4*)&Bs[buf][kk][tx * 4];
            #pragma unroll
            for (int i = 0; i < 4; i++)
                #pragma unroll
                for (int j = 0; j < 4; j++) acc[i][j] += av[i] * bv[j];
        }
        if (more) {
            int nb = 1 - buf;
            As[nb][ac0 + 0][ar] = pa.x; As[nb][ac0 + 1][ar] = pa.y;
            As[nb][ac0 + 2][ar] = pa.z; As[nb][ac0 + 3][ar] = pa.w;
            *(float4*)&Bs[nb][br][bc] = pb;
        }
        __syncthreads();
    }
    #pragma unroll
    for (int i = 0; i < 4; i++) {
        int r = m0 + ty * 4 + i;
        int c = n0 + tx * 4;
        float v[4];
        #pragma unroll
        for (int j = 0; j < 4; j++) {
            float t = acc[i][j];
            if (HASBIAS) t += bias[c + j];
            if (GELU) t = gelu_f(t);
            v[j] = t;
        }
        *(float4*)(C + (size_t)r * ldc + c) = *(float4*)v;
    }
}

// ---------------------------------------------------------------------------
// 5a. 64x128 GEMM, db + reg prefetch — for L4 only (K=1280, 2 n-blocks):
//     measured ~30 us better than 64x64 there (R12). NOT for conv5 —
//     hits the 128-VGPR cliff + 3x bank conflicts, 210->243 us (R12).
// ---------------------------------------------------------------------------
template <bool GELU, bool HASBIAS>
__global__ __launch_bounds__(256) void gemm_f32_64x128(
    const float* __restrict__ A, int lda,
    const float* __restrict__ B, int ldb, int K,
    const float* __restrict__ bias,
    float* __restrict__ C, int ldc) {
    __shared__ float As[2][16][64];
    __shared__ float Bs[2][16][128];
    int tid = threadIdx.x;
    int tx = tid & 15, ty = tid >> 4;
    int m0 = blockIdx.y * 64, n0 = blockIdx.x * 128;
    float acc[4][8];
    #pragma unroll
    for (int i = 0; i < 4; i++)
        #pragma unroll
        for (int j = 0; j < 8; j++) acc[i][j] = 0.0f;

    int ar = tid >> 2, ac0 = (tid & 3) * 4;
    const float* aptr = A + (size_t)(m0 + ar) * lda + ac0;
    int br = tid >> 5, bc = (tid & 31) * 4;
    const float* bptr = B + (size_t)br * ldb + n0 + bc;

    float4 pa = *(const float4*)(aptr);
    float4 pb0 = *(const float4*)(bptr);
    float4 pb1 = *(const float4*)(bptr + (size_t)8 * ldb);
    As[0][ac0 + 0][ar] = pa.x; As[0][ac0 + 1][ar] = pa.y;
    As[0][ac0 + 2][ar] = pa.z; As[0][ac0 + 3][ar] = pa.w;
    *(float4*)&Bs[0][br][bc] = pb0;
    *(float4*)&Bs[0][br + 8][bc] = pb1;
    __syncthreads();

    int nk = K >> 4;
    for (int t = 0; t < nk; t++) {
        int buf = t & 1;
        bool more = (t + 1) < nk;
        if (more) {
            int k0 = (t + 1) << 4;
            pa = *(const float4*)(aptr + k0);
            pb0 = *(const float4*)(bptr + (size_t)k0 * ldb);
            pb1 = *(const float4*)(bptr + (size_t)(k0 + 8) * ldb);
        }
        #pragma unroll
        for (int kk = 0; kk < 16; kk++) {
            float av[4], bv[8];
            *(float4*)&av[0] = *(const float4*)&As[buf][kk][ty * 4];
            *(float4*)&bv[0] = *(const float4*)&Bs[buf][kk][tx * 4];
            *(float4*)&bv[4] = *(const float4*)&Bs[buf][kk][64 + tx * 4];
            #pragma unroll
            for (int i = 0; i < 4; i++)
                #pragma unroll
                for (int j = 0; j < 8; j++) acc[i][j] += av[i] * bv[j];
        }
        if (more) {
            int nb = 1 - buf;
            As[nb][ac0 + 0][ar] = pa.x; As[nb][ac0 + 1][ar] = pa.y;
            As[nb][ac0 + 2][ar] = pa.z; As[nb][ac0 + 3][ar] = pa.w;
            *(float4*)&Bs[nb][br][bc] = pb0;
            *(float4*)&Bs[nb][br + 8][bc] = pb1;
        }
        __syncthreads();
    }
    #pragma unroll
    for (int i = 0; i < 4; i++) {
        int r = m0 + ty * 4 + i;
        #pragma unroll
        for (int hj = 0; hj < 2; hj++) {
            int c = n0 + hj * 64 + tx * 4;
            float v[4];
            #pragma unroll
            for (int j = 0; j < 4; j++) {
                float t = acc[i][hj * 4 + j];
                if (HASBIAS) t += bias[c + j];
                if (GELU) t = gelu_f(t);
                v[j] = t;
            }
            *(float4*)(C + (size_t)r * ldc + c) = *(float4*)v;
        }
    }
}

// ---------------------------------------------------------------------------
// 5b. conv5 GEMM: proven R11 128x128 2-barrier + fused BN column partials.
// ---------------------------------------------------------------------------
__global__ __launch_bounds__(256) void gemm_conv5_stats(
    const float* __restrict__ A, int lda,
    const float* __restrict__ B, int ldb, int K,
    float* __restrict__ C, int ldc,
    float* __restrict__ partS, float* __restrict__ partQ) {
    __shared__ float As[16][128];
    __shared__ float Bs[16][128];
    int tid = threadIdx.x;
    int tx = tid & 15, ty = tid >> 4;
    int m0 = blockIdx.y * 128, n0 = blockIdx.x * 128;
    float acc[8][8];
    #pragma unroll
    for (int i = 0; i < 8; i++)
        #pragma unroll
        for (int j = 0; j < 8; j++) acc[i][j] = 0.0f;

    int ar = tid >> 1, ac0 = (tid & 1) * 8;
    const float* aptr = A + (size_t)(m0 + ar) * lda + ac0;

    for (int k0 = 0; k0 < K; k0 += 16) {
        float4 a0 = *(const float4*)(aptr + k0);
        float4 a1 = *(const float4*)(aptr + k0 + 4);
        As[ac0 + 0][ar] = a0.x; As[ac0 + 1][ar] = a0.y;
        As[ac0 + 2][ar] = a0.z; As[ac0 + 3][ar] = a0.w;
        As[ac0 + 4][ar] = a1.x; As[ac0 + 5][ar] = a1.y;
        As[ac0 + 6][ar] = a1.z; As[ac0 + 7][ar] = a1.w;
        {
            int r = tid >> 5, c = (tid & 31) * 4;
            const float* bp = B + (size_t)(k0 + r) * ldb + n0 + c;
            float4 b0 = *(const float4*)bp;
            float4 b1 = *(const float4*)(bp + (size_t)8 * ldb);
            *(float4*)&Bs[r][c] = b0;
            *(float4*)&Bs[r + 8][c] = b1;
        }
        __syncthreads();
        #pragma unroll
        for (int kk = 0; kk < 16; kk++) {
            float av[8], bv[8];
            *(float4*)&av[0] = *(const float4*)&As[kk][ty * 4];
            *(float4*)&av[4] = *(const float4*)&As[kk][64 + ty * 4];
            *(float4*)&bv[0] = *(const float4*)&Bs[kk][tx * 4];
            *(float4*)&bv[4] = *(const float4*)&Bs[kk][64 + tx * 4];
            #pragma unroll
            for (int i = 0; i < 8; i++)
                #pragma unroll
                for (int j = 0; j < 8; j++) acc[i][j] += av[i] * bv[j];
        }
        __syncthreads();
    }
    #pragma unroll
    for (int hi = 0; hi < 2; hi++) {
        #pragma unroll
        for (int i = 0; i < 4; i++) {
            int r = m0 + hi * 64 + ty * 4 + i;
            #pragma unroll
            for (int hj = 0; hj < 2; hj++) {
                int c = n0 + hj * 64 + tx * 4;
                float v[4];
                #pragma unroll
                for (int j = 0; j < 4; j++) v[j] = acc[hi * 4 + i][hj * 4 + j];
                *(float4*)(C + (size_t)r * ldc + c) = *(float4*)v;
            }
        }
    }
    #pragma unroll
    for (int hj = 0; hj < 2; hj++) {
        #pragma unroll
        for (int j = 0; j < 4; j++) {
            int cl = hj * 64 + tx * 4 + j;
            float s = 0.0f, q = 0.0f;
            #pragma unroll
            for (int hi = 0; hi < 2; hi++)
                #pragma unroll
                for (int i = 0; i < 4; i++) {
                    float v = acc[hi * 4 + i][hj * 4 + j];
                    s += v; q += v * v;
                }
            As[ty][cl] = s;
            Bs[ty][cl] = q;
        }
    }
    __syncthreads();
    if (tid < 128) {
        float S = 0.0f, Q = 0.0f;
        #pragma unroll
        for (int tt = 0; tt < 16; tt++) { S += As[tt][tid]; Q += Bs[tt][tid]; }
        partS[(size_t)blockIdx.y * 1024 + n0 + tid] = S;
        partQ[(size_t)blockIdx.y * 1024 + n0 + tid] = Q;
    }
}

// ---------------------------------------------------------------------------
// 6. stats_reduce over 128 per-m-block partials (deterministic order)
// ---------------------------------------------------------------------------
__global__ __launch_bounds__(256) void stats_reduce(
    const float* __restrict__ partS, const float* __restrict__ partQ,
    const float* __restrict__ g, const float* __restrict__ be,
    float* __restrict__ scaleb, float* __restrict__ shiftb) {
    int e = blockIdx.x * 256 + threadIdx.x;
    if (e >= 1024) return;
    double s = 0.0, q = 0.0;
    for (int mb = 0; mb < 128; mb++) {
        s += (double)partS[(size_t)mb * 1024 + e];
        q += (double)partQ[(size_t)mb * 1024 + e];
    }
    double m = s * (1.0 / 16384.0);
    double v = q * (1.0 / 16384.0) - m * m;
    float sc = g[e] * (float)(1.0 / sqrt(v + 1e-5));
    scaleb[e] = sc;
    shiftb[e] = be[e] - (float)m * sc;
}

// ---------------------------------------------------------------------------
// 7. pool
// ---------------------------------------------------------------------------
__global__ __launch_bounds__(256) void pool_kernel(
    const float* __restrict__ f5, const float* __restrict__ scaleb,
    const float* __restrict__ shiftb, float* __restrict__ h) {
    int b = blockIdx.x >> 4;
    int g = blockIdx.x & 15;
    int e = g * 64 + (threadIdx.x & 63);
    int nlane = threadIdx.x >> 6;
    float sc = scaleb[e], sh = shiftb[e];
    float vmax = -FLT_BIG;
    double vsum = 0.0;
    for (int n = nlane; n < NPT; n += 4) {
        float v = f5[((size_t)b * NPT + n) * 1024 + e];
        v = gelu_f(v * sc + sh);
        vmax = fmaxf(vmax, v);
        vsum += (double)v;
    }
    __shared__ float smax[256];
    __shared__ double ssum[256];
    smax[threadIdx.x] = vmax;
    ssum[threadIdx.x] = vsum;
    __syncthreads();
    if (nlane == 0) {
        for (int i = 1; i < 4; i++) {
            vmax = fmaxf(vmax, smax[threadIdx.x + 64 * i]);
            vsum += ssum[threadIdx.x + 64 * i];
        }
        h[(size_t)b * 2048 + e] = vmax;
        h[(size_t)b * 2048 + 1024 + e] = (float)(vsum * (1.0 / 1024.0));
    }
}

// ---------------------------------------------------------------------------
// 8. FC head: split-K fp64 partials; fused reduce+BN+gelu.
// ---------------------------------------------------------------------------
__global__ __launch_bounds__(256) void fc_split(
    const float* __restrict__ X, const float* __restrict__ W,
    double* __restrict__ part, int Bn, int In, int Out, int KC) {
    int tid = blockIdx.x * 256 + threadIdx.x;
    if (tid >= Bn * Out * KC) return;
    int chunk = tid / (Bn * Out);
    int r = tid - chunk * (Bn * Out);
    int b = r / Out, j = r - b * Out;
    int len = In / KC;
    int i0 = chunk * len;
    const float* x = X + (size_t)b * In + i0;
    const float* w = W + (size_t)i0 * Out + j;
    double acc = 0.0;
    for (int i = 0; i < len; i++) acc += (double)x[i] * (double)w[(size_t)i * Out];
    part[tid] = acc;
}

__global__ __launch_bounds__(256) void fc_bn_gelu(
    const double* __restrict__ part, const float* __restrict__ bias,
    const float* __restrict__ g, const float* __restrict__ be,
    float* __restrict__ Y, int Out, int KC) {
    int j = blockIdx.x * 256 + threadIdx.x;
    if (j >= Out) return;
    float r[BSZ];
    for (int b = 0; b < BSZ; b++) {
        double acc = bias ? (double)bias[j] : 0.0;
        for (int c = 0; c < KC; c++) acc += part[(size_t)c * (BSZ * Out) + b * Out + j];
        r[b] = (float)acc;
    }
    double m = 0.0;
    for (int b = 0; b < BSZ; b++) m += (double)r[b];
    m /= (double)BSZ;
    double v = 0.0;
    for (int b = 0; b < BSZ; b++) {
        double dd = (double)r[b] - m;
        v += dd * dd;
    }
    v /= (double)BSZ;
    float sc = g[j] * (float)(1.0 / sqrt(v + 1e-5));
    float sh = be[j] - (float)m * sc;
    for (int b = 0; b < BSZ; b++) Y[b * Out + j] = gelu_f(r[b] * sc + sh);
}

__global__ __launch_bounds__(256) void fc_reduce(
    const double* __restrict__ part, const float* __restrict__ bias,
    float* __restrict__ Y, int Bn, int Out, int KC) {
    int r = blockIdx.x * 256 + threadIdx.x;
    if (r >= Bn * Out) return;
    int j = r % Out;
    double acc = bias ? (double)bias[j] : 0.0;
    for (int c = 0; c < KC; c++) acc += part[(size_t)c * (Bn * Out) + r];
    Y[r] = (float)acc;
}

// ---------------------------------------------------------------------------
extern "C" void kernel_launch(void* const* d_in, const int* in_sizes, int n_in,
                              void* d_out, int out_size, void* d_ws, size_t ws_size,
                              hipStream_t stream) {
    const float* x     = (const float*)d_in[0];
    const float* B_ff  = (const float*)d_in[1];
    const float* mlp_W = (const float*)d_in[2];
    const float* permx = (const float*)d_in[3];
    const float* W1 = (const float*)d_in[4];
    const float* b1 = (const float*)d_in[5];
    const float* S1 = (const float*)d_in[6];
    const float* W2 = (const float*)d_in[7];
    const float* b2 = (const float*)d_in[8];
    const float* S2 = (const float*)d_in[9];
    const float* W3 = (const float*)d_in[10];
    const float* b3 = (const float*)d_in[11];
    const float* S3 = (const float*)d_in[12];
    const float* W4 = (const float*)d_in[13];
    const float* b4 = (const float*)d_in[14];
    const float* S4 = (const float*)d_in[15];
    const float* W5 = (const float*)d_in[16];
    const float* g5 = (const float*)d_in[17];
    const float* be5 = (const float*)d_in[18];
    const float* L1 = (const float*)d_in[19];
    const float* g6 = (const float*)d_in[20];
    const float* be6 = (const float*)d_in[21];
    const float* L2 = (const float*)d_in[22];
    const float* bL2 = (const float*)d_in[23];
    const float* g7 = (const float*)d_in[24];
    const float* be7 = (const float*)d_in[25];
    const float* L3 = (const float*)d_in[26];
    const float* bL3 = (const float*)d_in[27];
    float* outp = (float*)d_out;

    const int BN = BSZ * NPT;  // 16384

    // workspace (float units; 16B-aligned). R11 liveness unions:
    //   f5 aliases Zbig; wz1..wz3 in Zbig tail beyond the L1-L3 Z extent;
    //   wz4 own slot; partC_S/Q (128x1024) + partF alias Pb.
    float* ws = (float*)d_ws;
    float* pts   = ws;                         // 49152
    int*   idxb  = (int*)(ws + 49152);         // 491520 ints
    float* Pb    = ws + 540672;                // 4423680
    float* feat  = Pb + 4423680;               // 8388608 (x1|x2|x3|x4, stride 512)
    float* Zbig  = feat + 8388608;             // 20971520 (max layer: 16384x1280)
    float* f5    = Zbig;                       // union: 16777216
    float* wz4   = Zbig + 20971520;            // 327680
    float* scb   = wz4 + 327680;               // 1024
    float* shb   = scb + 1024;                 // 1024
    float* hb    = shb + 1024;                 // 32768
    float* y1    = hb + 32768;                 // 8192
    float* y2    = y1 + 8192;                  // 4096
    float* wz1   = Zbig + 11010048;            // 2048   (Zbig tail, dead by L4 agg)
    float* wz2   = wz1 + 2048;                 // 40960
    float* wz3   = wz2 + 40960;                // 81920  (ends 11134976 < 16777216)
    float* partC_S = Pb;                       // 131072
    float* partC_Q = Pb + 131072;              // 131072
    double* partF  = (double*)(Pb + 262144);   // 131072 doubles
    size_t need_bytes = (size_t)((y2 + 4096) - ws) * sizeof(float);
    if (ws_size < need_bytes) return;

    // setup: transpose + all 4 WZ preps in one dispatch
    prep_all<<<dim3(1280, 5), 256, 0, stream>>>(
        x, pts, W1, S1, wz1, W2, S2, wz2, W3, S3, wz3, W4, S4, wz4);

    // fused kNN + basis (R11: top-2 cached selection)
    knn_basis_kernel<<<BN / 4, 256, 0, stream>>>(pts, B_ff, mlp_W, permx, idxb, Pb);

    // ---- layer 1: CIN=3, kpad=32, N=64 ----
    agg_kernel<3><<<BN, 256, 0, stream>>>(pts, 3, Pb, idxb, Zbig, 32);
    gemm_f32_64db<true, true><<<dim3(1, 256), 256, 0, stream>>>(
        Zbig, 32, wz1, 64, 32, b1, feat + 0, 512);
    // ---- layer 2: CIN=64, kpad=640, N=64 ----
    agg_v_kernel<64><<<BN, 256, 0, stream>>>(feat + 0, 512, Pb, idxb, Zbig, 640);
    gemm_f32_64db<true, true><<<dim3(1, 256), 256, 0, stream>>>(
        Zbig, 640, wz2, 64, 640, b2, feat + 64, 512);
    // ---- layer 3: CIN=64, kpad=640, N=128 ----
    agg_v_kernel<64><<<BN, 256, 0, stream>>>(feat + 64, 512, Pb, idxb, Zbig, 640);
    gemm_f32_64db<true, true><<<dim3(2, 256), 256, 0, stream>>>(
        Zbig, 640, wz3, 128, 640, b3, feat + 128, 512);
    // ---- layer 4: CIN=128, kpad=1280, N=256 -> 64x128 tile (R12 win) ----
    agg_v_kernel<128><<<BN, 256, 0, stream>>>(feat + 128, 512, Pb, idxb, Zbig, 1280);
    gemm_f32_64x128<true, true><<<dim3(2, 256), 256, 0, stream>>>(
        Zbig, 1280, wz4, 256, 1280, b4, feat + 256, 512);

    // ---- conv5 + fused BN partials: R11 128x128 (Zbig dead -> f5) ----
    gemm_conv5_stats<<<dim3(8, 128), 256, 0, stream>>>(
        feat, 512, W5, 1024, 512, f5, 1024, partC_S, partC_Q);

    stats_reduce<<<4, 256, 0, stream>>>(partC_S, partC_Q, g5, be5, scb, shb);
    pool_kernel<<<BSZ * 16, 256, 0, stream>>>(f5, scb, shb, hb);

    // ---- FC head ----
    fc_split<<<(BSZ * 512 * 16 + 255) / 256, 256, 0, stream>>>(hb, L1, partF, BSZ, 2048, 512, 16);
    fc_bn_gelu<<<2, 256, 0, stream>>>(partF, nullptr, g6, be6, y1, 512, 16);
    fc_split<<<(BSZ * 256 * 8 + 255) / 256, 256, 0, stream>>>(y1, L2, partF, BSZ, 512, 256, 8);
    fc_bn_gelu<<<1, 256, 0, stream>>>(partF, bL2, g7, be7, y2, 256, 8);
    fc_split<<<(BSZ * 40 * 4 + 255) / 256, 256, 0, stream>>>(y2, L3, partF, BSZ, 256, 40, 4);
    fc_reduce<<<(BSZ * 40 + 255) / 256, 256, 0, stream>>>(partF, bL3, outp, BSZ, 40, 4);
}